// Round 4
// baseline (317.754 us; speedup 1.0000x reference)
//
#include <hip/hip_runtime.h>
#include <hip/hip_bf16.h>
#include <cstdint>

typedef __bf16 bf16;
typedef bf16 bf16x8 __attribute__((ext_vector_type(8)));
typedef float f32x4 __attribute__((ext_vector_type(4)));
typedef uint32_t u32;

#define MFMA16(a, b, c) __builtin_amdgcn_mfma_f32_16x16x32_bf16(a, b, c, 0, 0, 0)

static constexpr int Bb = 2, Hh = 12, Nn = 2048, Cc = 768, HD = 64;
static constexpr float SCALE = 0.125f;        // HD^-0.5
static constexpr float LOG2E = 1.4426950408889634f;

__device__ inline u32 pkbf(float a, float b) {
    union { struct { uint16_t lo, hi; } s; u32 w; } u;
    u.s.lo = __builtin_bit_cast(uint16_t, (bf16)a);
    u.s.hi = __builtin_bit_cast(uint16_t, (bf16)b);
    return u.w;
}

// pinned 16B global load the compiler cannot sink/alias/track
__device__ __forceinline__ void gload(bf16x8& d, const bf16* p) {
    asm volatile("global_load_dwordx4 %0, %1, off" : "=v"(d) : "v"(p));
}

#define VMWAIT(N) do { asm volatile("s_waitcnt vmcnt(" #N ")" ::); \
                       __builtin_amdgcn_sched_barrier(0); } while (0)

// ---------------- fp32 -> bf16 conversion (8 elems/thread) ----------------
__global__ __launch_bounds__(256) void cvt_f32_bf16(const float* __restrict__ in,
                                                    bf16* __restrict__ out, int n8) {
    int i = blockIdx.x * blockDim.x + threadIdx.x;
    if (i >= n8) return;
    const float4* p = reinterpret_cast<const float4*>(in) + (size_t)i * 2;
    float4 v0 = p[0], v1 = p[1];
    bf16x8 o;
    o[0] = (bf16)v0.x; o[1] = (bf16)v0.y; o[2] = (bf16)v0.z; o[3] = (bf16)v0.w;
    o[4] = (bf16)v1.x; o[5] = (bf16)v1.y; o[6] = (bf16)v1.z; o[7] = (bf16)v1.w;
    reinterpret_cast<bf16x8*>(out)[i] = o;
}

__global__ __launch_bounds__(256) void cvt4_f32_bf16(const float* __restrict__ s0, const float* __restrict__ s1,
                                                     const float* __restrict__ s2, const float* __restrict__ s3,
                                                     bf16* __restrict__ d0, bf16* __restrict__ d1,
                                                     bf16* __restrict__ d2, bf16* __restrict__ d3, int n8) {
    int i = blockIdx.x * blockDim.x + threadIdx.x;
    if (i >= n8) return;
    const float* in = blockIdx.y == 0 ? s0 : blockIdx.y == 1 ? s1 : blockIdx.y == 2 ? s2 : s3;
    bf16* out = blockIdx.y == 0 ? d0 : blockIdx.y == 1 ? d1 : blockIdx.y == 2 ? d2 : d3;
    const float4* p = reinterpret_cast<const float4*>(in) + (size_t)i * 2;
    float4 v0 = p[0], v1 = p[1];
    bf16x8 o;
    o[0] = (bf16)v0.x; o[1] = (bf16)v0.y; o[2] = (bf16)v0.z; o[3] = (bf16)v0.w;
    o[4] = (bf16)v1.x; o[5] = (bf16)v1.y; o[6] = (bf16)v1.z; o[7] = (bf16)v1.w;
    reinterpret_cast<bf16x8*>(out)[i] = o;
}

// ---------------- fused QKV GEMM: W = [Wq;Wk;Wv] (2304 x 768) ----------------
__global__ __launch_bounds__(256) void gemm_qkv(const bf16* __restrict__ X,
                                                const bf16* __restrict__ W,
                                                bf16* __restrict__ Qb,
                                                bf16* __restrict__ Kb,
                                                bf16* __restrict__ Vtb) {
    constexpr int K = Cc;
    const int m0  = blockIdx.x * 128;
    const int grp = blockIdx.y / 12;
    const int j0  = (blockIdx.y % 12) * 64;
    const int w   = threadIdx.x >> 6;
    const int l   = threadIdx.x & 63;
    const int lr  = l & 15;
    const int lg  = l >> 4;
    const int mw  = m0 + w * 32;

    f32x4 acc[2][4] = {};
    const bf16* xA = X + (size_t)(mw + lr) * K + lg * 8;
    const bf16* wB = W + (size_t)(blockIdx.y * 64 + lr) * K + lg * 8;

    for (int k = 0; k < K; k += 32) {
        bf16x8 a[2], b[4];
        a[0] = *reinterpret_cast<const bf16x8*>(xA + k);
        a[1] = *reinterpret_cast<const bf16x8*>(xA + (size_t)16 * K + k);
#pragma unroll
        for (int c = 0; c < 4; c++)
            b[c] = *reinterpret_cast<const bf16x8*>(wB + (size_t)(c * 16) * K + k);
#pragma unroll
        for (int r = 0; r < 2; r++)
#pragma unroll
            for (int c = 0; c < 4; c++)
                acc[r][c] = MFMA16(a[r], b[c], acc[r][c]);
    }

#pragma unroll
    for (int r = 0; r < 2; r++)
#pragma unroll
        for (int c = 0; c < 4; c++)
#pragma unroll
            for (int j = 0; j < 4; j++) {
                const int m   = mw + r * 16 + lg * 4 + j;
                const int col = j0 + c * 16 + lr;
                const int bb = m >> 11, n = m & 2047;
                const int h = col >> 6, hd = col & 63;
                const float v = acc[r][c][j];
                if (grp == 0) {
                    Qb[(((size_t)(bb * Hh + h)) * Nn + n) * HD + hd] = (bf16)(v * SCALE);
                } else if (grp == 1) {
                    Kb[(((size_t)(bb * Hh + h)) * Nn + n) * HD + hd] = (bf16)v;
                } else {
                    Vtb[(((size_t)(bb * Hh + h)) * HD + hd) * Nn + n] = (bf16)v;
                }
            }
}

// ---------------- output projection: BM=64 tiles ----------------
__global__ __launch_bounds__(256) void gemm_proj(const bf16* __restrict__ X,
                                                 const bf16* __restrict__ W,
                                                 const float* __restrict__ bias,
                                                 float* __restrict__ Y) {
    constexpr int K = Cc;
    const int m0 = blockIdx.x * 64;
    const int j0 = blockIdx.y * 64;
    const int w  = threadIdx.x >> 6;
    const int l  = threadIdx.x & 63;
    const int lr = l & 15;
    const int lg = l >> 4;
    const int mw = m0 + w * 16;

    f32x4 acc[4] = {};
    const bf16* xA = X + (size_t)(mw + lr) * K + lg * 8;
    const bf16* wB = W + (size_t)(j0 + lr) * K + lg * 8;

    for (int k = 0; k < K; k += 32) {
        bf16x8 a = *reinterpret_cast<const bf16x8*>(xA + k);
        bf16x8 b[4];
#pragma unroll
        for (int c = 0; c < 4; c++)
            b[c] = *reinterpret_cast<const bf16x8*>(wB + (size_t)(c * 16) * K + k);
#pragma unroll
        for (int c = 0; c < 4; c++)
            acc[c] = MFMA16(a, b[c], acc[c]);
    }

#pragma unroll
    for (int c = 0; c < 4; c++)
#pragma unroll
        for (int j = 0; j < 4; j++) {
            const int m   = mw + lg * 4 + j;
            const int col = j0 + c * 16 + lr;
            Y[(size_t)m * Cc + col] = acc[c][j] + bias[col];
        }
}

// ---------------- flash attention v4: asm-load pipeline, counted vmcnt ----
// 1 wave/block, 16 q-rows. ALL global loads via inline asm; only waits are
// the hand-counted vmcnt(8)/vmcnt(0). Steady state: 16 loads in flight.
__global__ __launch_bounds__(64, 3) void attn_kernel(const bf16* __restrict__ Q,
                                                     const bf16* __restrict__ Km,
                                                     const bf16* __restrict__ Vt,
                                                     bf16* __restrict__ AO) {
    const int bid = blockIdx.x;
    const int qb  = bid & 127;
    const int bh  = bid >> 7;
    const int l   = threadIdx.x;
    const int lr  = l & 15;
    const int lg  = l >> 4;
    const int q0  = qb * 16;

    __shared__ u32   p_lds[16 * 36];
    __shared__ float o_lds[64 * 17];

    const bf16* Kbase = Km + (size_t)bh * Nn * HD;
    const bf16* Vbase = Vt + (size_t)bh * HD * Nn;

    f32x4 acc[4] = {};
    float mrun = -INFINITY, lrun = 0.f;

    bf16x8 qf0, qf1, kk[8], vv[8];

    auto issueK = [&](int t) {
        const bf16* p = Kbase + ((size_t)(t * 64) + lr) * HD + lg * 8;
#pragma unroll
        for (int st = 0; st < 4; st++) {
            gload(kk[st * 2],     p + (size_t)(st * 16) * HD);
            gload(kk[st * 2 + 1], p + (size_t)(st * 16) * HD + 32);
        }
    };
    auto issueV = [&](int t) {
        const bf16* p = Vbase + (size_t)lr * Nn + t * 64 + lg * 8;
#pragma unroll
        for (int c = 0; c < 4; c++) {
            gload(vv[c * 2],     p + (size_t)(c * 16) * Nn);
            gload(vv[c * 2 + 1], p + (size_t)(c * 16) * Nn + 32);
        }
    };

    // ---- prologue: Q (2) + K0 (8) + V0 (8) in flight ----
    const bf16* Qp = Q + ((size_t)bh * Nn + q0 + lr) * HD + lg * 8;
    gload(qf0, Qp);
    gload(qf1, Qp + 32);
    issueK(0);
    issueV(0);
    VMWAIT(16);                         // Q ready; K0,V0 still in flight

    const f32x4 fz = {0.f, 0.f, 0.f, 0.f};
    f32x4 s[4];

    auto QK = [&]() {
        __builtin_amdgcn_s_setprio(1);
#pragma unroll
        for (int st = 0; st < 4; st++) {
            s[st] = MFMA16(kk[st * 2], qf0, fz);
            s[st] = MFMA16(kk[st * 2 + 1], qf1, s[st]);
        }
        __builtin_amdgcn_s_setprio(0);
    };
    auto SOFTMAX_PV = [&]() {
        float mt = s[0][0];
#pragma unroll
        for (int st = 0; st < 4; st++)
#pragma unroll
            for (int j = 0; j < 4; j++) mt = fmaxf(mt, s[st][j]);
        mt = fmaxf(mt, __shfl_xor(mt, 16));
        mt = fmaxf(mt, __shfl_xor(mt, 32));

        const float mnew  = fmaxf(mrun, mt);
        const float alpha = exp2f((mrun - mnew) * LOG2E);
        const float c1    = mnew * LOG2E;
        float p[4][4];
        float rs = 0.f;
#pragma unroll
        for (int st = 0; st < 4; st++)
#pragma unroll
            for (int j = 0; j < 4; j++) {
                p[st][j] = exp2f(fmaf(s[st][j], LOG2E, -c1));
                rs += p[st][j];
            }
        rs += __shfl_xor(rs, 16);
        rs += __shfl_xor(rs, 32);
        lrun = lrun * alpha + rs;
        mrun = mnew;
#pragma unroll
        for (int c = 0; c < 4; c++) acc[c] *= alpha;

#pragma unroll
        for (int st = 0; st < 4; st++) {
            u32 w0 = pkbf(p[st][0], p[st][1]);
            u32 w1 = pkbf(p[st][2], p[st][3]);
            *reinterpret_cast<uint2*>(&p_lds[lr * 36 + st * 8 + lg * 2]) = make_uint2(w0, w1);
        }
        asm volatile("s_waitcnt lgkmcnt(0)" ::: "memory");
        __builtin_amdgcn_sched_barrier(0);
        const bf16x8 pa0 = *reinterpret_cast<const bf16x8*>(&p_lds[lr * 36 + lg * 4]);
        const bf16x8 pa1 = *reinterpret_cast<const bf16x8*>(&p_lds[lr * 36 + 16 + lg * 4]);

        __builtin_amdgcn_s_setprio(1);
#pragma unroll
        for (int c = 0; c < 4; c++) {
            acc[c] = MFMA16(vv[c * 2], pa0, acc[c]);
            acc[c] = MFMA16(vv[c * 2 + 1], pa1, acc[c]);
        }
        __builtin_amdgcn_s_setprio(0);
    };

    // ---- main loop: tiles 0..30, always prefetching t+1 ----
#pragma unroll 1
    for (int t = 0; t < 31; ++t) {
        VMWAIT(8);                      // K(t) ready (V(t) still in flight)
        QK();
        issueK(t + 1);                  // reuse kk; WAR after QK consumed it
        VMWAIT(8);                      // V(t) ready (K(t+1) in flight)
        SOFTMAX_PV();
        issueV(t + 1);                  // reuse vv; WAR after PV consumed it
    }
    // ---- tail: tile 31, nothing left to prefetch ----
    VMWAIT(8);                          // K31 ready
    QK();
    VMWAIT(0);                          // V31 ready
    SOFTMAX_PV();

    // ---- epilogue ----
    const float rinv = 1.0f / lrun;
#pragma unroll
    for (int c = 0; c < 4; c++)
#pragma unroll
        for (int j = 0; j < 4; j++)
            o_lds[(c * 16 + lg * 4 + j) * 17 + lr] = acc[c][j] * rinv;
    asm volatile("s_waitcnt lgkmcnt(0)" ::: "memory");
    __builtin_amdgcn_sched_barrier(0);

    const int bb = bh / Hh, h = bh % Hh;
    const int qq = l >> 2, dc = (l & 3) * 16;
    bf16x8 o0, o1;
#pragma unroll
    for (int dd = 0; dd < 8; dd++) o0[dd] = (bf16)o_lds[(dc + dd) * 17 + qq];
#pragma unroll
    for (int dd = 0; dd < 8; dd++) o1[dd] = (bf16)o_lds[(dc + 8 + dd) * 17 + qq];
    bf16* dst = AO + ((size_t)(bb * Nn) + q0 + qq) * Cc + h * 64 + dc;
    *reinterpret_cast<bf16x8*>(dst) = o0;
    *reinterpret_cast<bf16x8*>(dst + 8) = o1;
}

// ---------------- launch ----------------
extern "C" void kernel_launch(void* const* d_in, const int* in_sizes, int n_in,
                              void* d_out, int out_size, void* d_ws, size_t ws_size,
                              hipStream_t stream) {
    const float* x  = (const float*)d_in[0];
    const float* Wq = (const float*)d_in[1];
    const float* Wk = (const float*)d_in[2];
    const float* Wv = (const float*)d_in[3];
    const float* Wo = (const float*)d_in[4];
    const float* bo = (const float*)d_in[5];

    const size_t XB    = 0;
    const size_t WQKVB = XB + 6291456;
    const size_t WOB   = WQKVB + 3538944;
    const size_t QB    = WOB + 1179648;
    const size_t KB    = QB + 6291456;
    const size_t VTB   = KB + 6291456;
    const size_t AOB   = VTB + 6291456;
    const size_t NEED  = AOB + 6291456;
    if (ws_size < NEED) return;

    char* ws = (char*)d_ws;
    bf16* xb   = (bf16*)(ws + XB);
    bf16* wqkv = (bf16*)(ws + WQKVB);
    bf16* wob  = (bf16*)(ws + WOB);
    bf16* Qb   = (bf16*)(ws + QB);
    bf16* Kb   = (bf16*)(ws + KB);
    bf16* Vtb  = (bf16*)(ws + VTB);
    bf16* AOb  = (bf16*)(ws + AOB);

    cvt_f32_bf16<<<1536, 256, 0, stream>>>(x, xb, (Bb * Nn * Cc) / 8);
    cvt4_f32_bf16<<<dim3(288, 4), 256, 0, stream>>>(Wq, Wk, Wv, Wo,
                                                    wqkv, wqkv + 589824, wqkv + 1179648, wob,
                                                    (Cc * Cc) / 8);

    gemm_qkv<<<dim3(32, 36), 256, 0, stream>>>(xb, wqkv, Qb, Kb, Vtb);

    attn_kernel<<<Bb * Hh * (Nn / 16), 64, 0, stream>>>(Qb, Kb, Vtb, AOb);

    gemm_proj<<<dim3(64, 12), 256, 0, stream>>>(AOb, wob, bo, (float*)d_out);
}